// Round 4
// baseline (8578.999 us; speedup 1.0000x reference)
//
#include <hip/hip_runtime.h>
#include <hip/hip_cooperative_groups.h>
#include <stdint.h>

namespace cg = cooperative_groups;

#define BB 64
#define DD 512
#define HH 1024
#define VV 32000
#define T_STEPS 50
#define G3 3072
#define NT 250      // logits col-tiles (128 cols each)
#define GHT 24      // gh/gi col-tiles (128 cols each)
#define UT 12000    // U tiles: 500 row-chunks x 24 col-tiles

typedef __attribute__((ext_vector_type(8))) short bf16x8;
typedef __attribute__((ext_vector_type(4))) float f32x4;
typedef unsigned long long u64;
typedef unsigned short ushort_t;

__device__ __forceinline__ uint32_t rotl32(uint32_t x, int d) {
  return (x << d) | (x >> (32 - d));
}

// JAX threefry2x32 (20 rounds) — verified exact in rounds 1-2.
__device__ __forceinline__ void threefry2x32(uint32_t k0, uint32_t k1,
                                             uint32_t& x0, uint32_t& x1) {
  uint32_t ks0 = k0, ks1 = k1, ks2 = k0 ^ k1 ^ 0x1BD11BDAu;
  x0 += ks0; x1 += ks1;
#define TF_R(r) { x0 += x1; x1 = rotl32(x1, (r)); x1 ^= x0; }
  TF_R(13) TF_R(15) TF_R(26) TF_R(6)
  x0 += ks1; x1 += ks2 + 1u;
  TF_R(17) TF_R(29) TF_R(16) TF_R(24)
  x0 += ks2; x1 += ks0 + 2u;
  TF_R(13) TF_R(15) TF_R(26) TF_R(6)
  x0 += ks0; x1 += ks1 + 3u;
  TF_R(17) TF_R(29) TF_R(16) TF_R(24)
  x0 += ks1; x1 += ks2 + 4u;
  TF_R(13) TF_R(15) TF_R(26) TF_R(6)
  x0 += ks2; x1 += ks0 + 5u;
#undef TF_R
}

__device__ __forceinline__ uint32_t f2bf(float f) {
  uint32_t u = __float_as_uint(f);
  return (u + 0x7fffu + ((u >> 16) & 1u)) >> 16;
}
__device__ __forceinline__ float bf2f(uint32_t b) { return __uint_as_float(b << 16); }

__device__ __forceinline__ u64 packkey(float v, int c) {
  uint32_t s = __float_as_uint(v);
  uint32_t mo = (s & 0x80000000u) ? ~s : (s | 0x80000000u);
  return ((u64)mo << 32) | (uint32_t)(~(uint32_t)c);
}
__device__ __forceinline__ u64 umax64(u64 a, u64 b) { return a > b ? a : b; }

union BF8 { uint32_t u[4]; bf16x8 v; };

__device__ __forceinline__ void split8(const float* f, bf16x8& hi, bf16x8& lo) {
  BF8 H, L;
#pragma unroll
  for (int i = 0; i < 4; ++i) {
    float a = f[2 * i], b = f[2 * i + 1];
    uint32_t ha = f2bf(a), hb = f2bf(b);
    float ra = a - bf2f(ha), rb = b - bf2f(hb);
    H.u[i] = ha | (hb << 16);
    L.u[i] = f2bf(ra) | (f2bf(rb) << 16);
  }
  hi = H.v; lo = L.v;
}

// 512-thread (8-wave) 64x128 output tile: acc += A[64][K] @ Bw[n0..n0+127][K]^T
// Same K-order / split-precision math as the verified round-2 kernel.
template<bool AF32>
__device__ __forceinline__ void mfma_tile512(
    ushort_t (*__restrict__ bhS)[40], ushort_t (*__restrict__ blS)[40],
    const ushort_t* __restrict__ Ahi, const ushort_t* __restrict__ Alo,
    const float* __restrict__ Af, int lda,
    const float* __restrict__ Bw, int K, int n0,
    f32x4 acc[2][2])
{
  const int tid = threadIdx.x;
  const int lane = tid & 63, w = tid >> 6;
  const int l15 = lane & 15, q = lane >> 4;
  const int rw = (w >> 2) * 32, cw = (w & 3) * 32;
  const int srow = tid >> 2, schunk = (tid & 3) * 8;   // 128 rows x 32 k-chunk

  for (int k0 = 0; k0 < K; k0 += 32) {
    const float* bp = Bw + (size_t)(n0 + srow) * K + k0 + schunk;
    float4 v0 = *(const float4*)bp;
    float4 v1 = *(const float4*)(bp + 4);

    bf16x8 ah[2], al[2];
#pragma unroll
    for (int m = 0; m < 2; ++m) {
      if constexpr (AF32) {
        const float* ap = Af + (size_t)(rw + 16 * m + l15) * lda + k0 + 8 * q;
        float4 a0 = *(const float4*)ap;
        float4 a1 = *(const float4*)(ap + 4);
        float f[8] = {a0.x, a0.y, a0.z, a0.w, a1.x, a1.y, a1.z, a1.w};
        split8(f, ah[m], al[m]);
      } else {
        const size_t ao = (size_t)(rw + 16 * m + l15) * lda + k0 + 8 * q;
        ah[m] = *(const bf16x8*)(Ahi + ao);
        al[m] = *(const bf16x8*)(Alo + ao);
      }
    }

    __syncthreads();
    {
      float f[8] = {v0.x, v0.y, v0.z, v0.w, v1.x, v1.y, v1.z, v1.w};
      bf16x8 bh, bl;
      split8(f, bh, bl);
      *(bf16x8*)&bhS[srow][schunk] = bh;
      *(bf16x8*)&blS[srow][schunk] = bl;
    }
    __syncthreads();

    bf16x8 bhf[2], blf[2];
#pragma unroll
    for (int n = 0; n < 2; ++n) {
      bhf[n] = *(const bf16x8*)&bhS[cw + 16 * n + l15][8 * q];
      blf[n] = *(const bf16x8*)&blS[cw + 16 * n + l15][8 * q];
    }
#pragma unroll
    for (int m = 0; m < 2; ++m)
#pragma unroll
      for (int n = 0; n < 2; ++n) {
        acc[m][n] = __builtin_amdgcn_mfma_f32_16x16x32_bf16(ah[m], bhf[n], acc[m][n], 0, 0, 0);
        acc[m][n] = __builtin_amdgcn_mfma_f32_16x16x32_bf16(ah[m], blf[n], acc[m][n], 0, 0, 0);
        acc[m][n] = __builtin_amdgcn_mfma_f32_16x16x32_bf16(al[m], bhf[n], acc[m][n], 0, 0, 0);
      }
  }
}

__device__ __forceinline__ void store_tile512(f32x4 acc[2][2], float* __restrict__ C,
                                              int ldc, int n0)
{
  const int tid = threadIdx.x, lane = tid & 63, w = tid >> 6;
  const int l15 = lane & 15, q = lane >> 4;
  const int rw = (w >> 2) * 32, cw = (w & 3) * 32;
#pragma unroll
  for (int m = 0; m < 2; ++m)
#pragma unroll
    for (int n = 0; n < 2; ++n)
#pragma unroll
      for (int r = 0; r < 4; ++r)
        C[(size_t)(rw + 16 * m + 4 * q + r) * ldc + n0 + cw + 16 * n + l15] = acc[m][n][r];
}

// logits store(+bias) + fused gumbel-argmax partial per batch row (verified math)
__device__ __forceinline__ void sample_epi512(
    f32x4 acc[2][2], u64 (*__restrict__ scr)[4],
    const float* __restrict__ bias, float* __restrict__ C, int n0,
    u64* __restrict__ partial, int jobid, int t)
{
  const int tid = threadIdx.x, lane = tid & 63, w = tid >> 6;
  const int l15 = lane & 15, q = lane >> 4;
  const int rw = (w >> 2) * 32, cw = (w & 3) * 32;

  uint32_t kt0 = 0u, kt1 = (uint32_t)t;
  threefry2x32(0u, 42u, kt0, kt1);

  u64 bk[2][4];
#pragma unroll
  for (int m = 0; m < 2; ++m)
#pragma unroll
    for (int r = 0; r < 4; ++r) bk[m][r] = 0ull;

#pragma unroll
  for (int m = 0; m < 2; ++m)
#pragma unroll
    for (int n = 0; n < 2; ++n)
#pragma unroll
      for (int r = 0; r < 4; ++r) {
        int row = rw + 16 * m + 4 * q + r;          // batch index
        int col = n0 + cw + 16 * n + l15;           // vocab index
        float val = acc[m][n][r] + bias[col];
        C[(size_t)row * VV + col] = val;
        uint32_t c0 = 0u, c1 = (uint32_t)(row * VV + col);
        threefry2x32(kt0, kt1, c0, c1);
        uint32_t bits = c0 ^ c1;
        float u = __uint_as_float((bits >> 9) | 0x3f800000u) - 1.0f;
        if (u == 0.0f) u = 1.17549435e-38f;
        float g = -__logf(-__logf(u));
        bk[m][r] = umax64(bk[m][r], packkey(val + g, col));
      }
#pragma unroll
  for (int off = 1; off < 16; off <<= 1)
#pragma unroll
    for (int m = 0; m < 2; ++m)
#pragma unroll
      for (int r = 0; r < 4; ++r)
        bk[m][r] = umax64(bk[m][r], (u64)__shfl_xor((long long)bk[m][r], off, 64));

  if (l15 == 0) {
#pragma unroll
    for (int m = 0; m < 2; ++m)
#pragma unroll
      for (int r = 0; r < 4; ++r)
        scr[rw + 16 * m + 4 * q + r][w & 3] = bk[m][r];
  }
  __syncthreads();
  if (tid < 64) {
    u64 f = umax64(umax64(scr[tid][0], scr[tid][1]),
                   umax64(scr[tid][2], scr[tid][3]));
    partial[(size_t)tid * NT + jobid] = f;
  }
  __syncthreads();
}

// block-wide argmax over the 250 per-tile partials of batch row b
__device__ __forceinline__ int finish_reduce(const u64* __restrict__ partial,
                                             int b, u64* __restrict__ sred)
{
  const int tid = threadIdx.x;
  u64 best = 0;
  if (tid < NT) best = partial[(size_t)b * NT + tid];
  sred[tid] = best;
  __syncthreads();
  for (int s = 256; s > 0; s >>= 1) {
    if (tid < s) sred[tid] = umax64(sred[tid], sred[tid + s]);
    __syncthreads();
  }
  return (int)(~(uint32_t)sred[0]);
}

__device__ __forceinline__ void fuse_elem(
    const float* __restrict__ gir, const float* __restrict__ ghr,
    const float* __restrict__ bih, const float* __restrict__ bhh,
    float* __restrict__ h, ushort_t* __restrict__ hhi, ushort_t* __restrict__ hlo,
    int b, int j)
{
  int i = b * HH + j;
  float ir  = gir[j]        + bih[j],        hr = ghr[j]        + bhh[j];
  float iz  = gir[j + 1024] + bih[j + 1024], hz = ghr[j + 1024] + bhh[j + 1024];
  float in_ = gir[j + 2048] + bih[j + 2048], hn = ghr[j + 2048] + bhh[j + 2048];
  float r = 1.f / (1.f + expf(-(ir + hr)));
  float z = 1.f / (1.f + expf(-(iz + hz)));
  float n = tanhf(in_ + r * hn);
  float hv = (1.f - z) * n + z * h[i];
  h[i] = hv;
  uint32_t hb = f2bf(hv);
  hhi[i] = (ushort_t)hb;
  hlo[i] = (ushort_t)f2bf(hv - bf2f(hb));
}

// ---------------- cooperative mega-kernel ----------------
template<bool USE_U>
__global__ __launch_bounds__(512, 2) void decoder_all(
    const float* __restrict__ seq, const float* __restrict__ emb,
    const float* __restrict__ Wih, const float* __restrict__ Whh,
    const float* __restrict__ bih, const float* __restrict__ bhh,
    const float* __restrict__ fcw, const float* __restrict__ fcb,
    const int* __restrict__ eos,
    float* __restrict__ idx_out, float* __restrict__ log_out,
    float* __restrict__ U, float* __restrict__ h,
    ushort_t* __restrict__ hhi, ushort_t* __restrict__ hlo,
    float* __restrict__ gh, float* __restrict__ gi,
    ushort_t* __restrict__ xh, ushort_t* __restrict__ xl,
    u64* __restrict__ partial)
{
  cg::grid_group grid = cg::this_grid();
  __shared__ ushort_t bhS[128][40];
  __shared__ ushort_t blS[128][40];
  __shared__ u64 scr[64][4];
  __shared__ u64 sred[512];
  const int bid = blockIdx.x, tid = threadIdx.x;
  const int GRD = gridDim.x;
  const int eosv = eos[0];

  // init: h = seq + split; (fallback) x = emb[eos] split
  for (int i = bid * 512 + tid; i < BB * HH; i += GRD * 512) {
    float v = seq[i];
    h[i] = v;
    uint32_t hb = f2bf(v);
    hhi[i] = (ushort_t)hb;
    hlo[i] = (ushort_t)f2bf(v - bf2f(hb));
  }
  if constexpr (!USE_U) {
    for (int i = bid * 512 + tid; i < BB * DD; i += GRD * 512) {
      float v = emb[(size_t)eosv * DD + (i & (DD - 1))];
      uint32_t hb = f2bf(v);
      xh[i] = (ushort_t)hb;
      xl[i] = (ushort_t)f2bf(v - bf2f(hb));
    }
  }
  grid.sync();
  if constexpr (USE_U) {
    // U = emb @ Wih^T (one-time) + gh(h_0)
    for (int tile = bid; tile < UT + GHT; tile += GRD) {
      f32x4 acc[2][2] = {};
      if (tile < UT) {
        int r0 = (tile / 24) * 64, c0 = (tile % 24) * 128;
        mfma_tile512<true>(bhS, blS, nullptr, nullptr, emb + (size_t)r0 * DD, DD,
                           Wih, DD, c0, acc);
        store_tile512(acc, U + (size_t)r0 * G3, G3, c0);
      } else {
        int g = tile - UT;
        mfma_tile512<false>(bhS, blS, hhi, hlo, nullptr, HH, Whh, HH, g * 128, acc);
        store_tile512(acc, gh, G3, g * 128);
      }
    }
  }
  grid.sync();

  for (int t = 0; t <= T_STEPS; ++t) {
    // ---- P1: inline finish(t-1) (+ fuse for USE_U / x-gather for !USE_U)
    for (int i0 = bid * 512; i0 < BB * HH; i0 += GRD * 512) {
      const int b = i0 >> 10, half = (i0 >> 9) & 1;
      int idx;
      if (t == 0) idx = eosv;
      else idx = finish_reduce(partial, b, sred);
      if (t > 0 && half == 0 && tid == 0)
        idx_out[(size_t)(t - 1) * BB + b] = (float)idx;
      if (t < T_STEPS) {
        if constexpr (USE_U) {
          const int j = (half << 9) + tid;
          fuse_elem(U + (size_t)idx * G3, gh + (size_t)b * G3, bih, bhh,
                    h, hhi, hlo, b, j);
        } else {
          if (half == 0) {
            float v = emb[(size_t)idx * DD + tid];
            uint32_t hb = f2bf(v);
            xh[(size_t)b * DD + tid] = (ushort_t)hb;
            xl[(size_t)b * DD + tid] = (ushort_t)f2bf(v - bf2f(hb));
          }
        }
      }
    }
    if (t == T_STEPS) break;
    grid.sync();

    if constexpr (!USE_U) {
      // gi = x @ Wih^T  ||  gh = h @ Whh^T
      for (int job = bid; job < 2 * GHT; job += GRD) {
        f32x4 acc[2][2] = {};
        if (job < GHT) {
          mfma_tile512<false>(bhS, blS, xh, xl, nullptr, DD, Wih, DD, job * 128, acc);
          store_tile512(acc, gi, G3, job * 128);
        } else {
          int g = job - GHT;
          mfma_tile512<false>(bhS, blS, hhi, hlo, nullptr, HH, Whh, HH, g * 128, acc);
          store_tile512(acc, gh, G3, g * 128);
        }
      }
      grid.sync();
      for (int i0 = bid * 512; i0 < BB * HH; i0 += GRD * 512) {
        const int b = i0 >> 10, half = (i0 >> 9) & 1;
        const int j = (half << 9) + tid;
        fuse_elem(gi + (size_t)b * G3, gh + (size_t)b * G3, bih, bhh,
                  h, hhi, hlo, b, j);
      }
      grid.sync();
    }

    // ---- P2: logits + sampling partials (|| gh(h_new) for USE_U)
    const int NJ = USE_U ? (NT + GHT) : NT;
    for (int job = bid; job < NJ; job += GRD) {
      f32x4 acc[2][2] = {};
      if (job < NT) {
        mfma_tile512<false>(bhS, blS, hhi, hlo, nullptr, HH, fcw, HH, job * 128, acc);
        sample_epi512(acc, scr, fcb, log_out + (size_t)t * BB * VV, job * 128,
                      partial, job, t);
      } else {
        int g = job - NT;
        mfma_tile512<false>(bhS, blS, hhi, hlo, nullptr, HH, Whh, HH, g * 128, acc);
        store_tile512(acc, gh, G3, g * 128);
      }
    }
    grid.sync();
  }
}

// ---------------- legacy fallback (4 launches/step, proven structure) ----------------
__global__ __launch_bounds__(512) void k_init(
    const float* __restrict__ seq, const float* __restrict__ emb,
    const int* __restrict__ eos, float* __restrict__ h,
    ushort_t* __restrict__ hhi, ushort_t* __restrict__ hlo,
    ushort_t* __restrict__ xh, ushort_t* __restrict__ xl)
{
  const int eosv = eos[0];
  for (int i = blockIdx.x * 512 + threadIdx.x; i < BB * HH; i += gridDim.x * 512) {
    float v = seq[i];
    h[i] = v;
    uint32_t hb = f2bf(v);
    hhi[i] = (ushort_t)hb;
    hlo[i] = (ushort_t)f2bf(v - bf2f(hb));
  }
  for (int i = blockIdx.x * 512 + threadIdx.x; i < BB * DD; i += gridDim.x * 512) {
    float v = emb[(size_t)eosv * DD + (i & (DD - 1))];
    uint32_t hb = f2bf(v);
    xh[i] = (ushort_t)hb;
    xl[i] = (ushort_t)f2bf(v - bf2f(hb));
  }
}

__global__ __launch_bounds__(512, 2) void k_gates(
    const ushort_t* __restrict__ xh, const ushort_t* __restrict__ xl,
    const ushort_t* __restrict__ hhi, const ushort_t* __restrict__ hlo,
    const float* __restrict__ Wih, const float* __restrict__ Whh,
    float* __restrict__ gi, float* __restrict__ gh)
{
  __shared__ ushort_t bhS[128][40];
  __shared__ ushort_t blS[128][40];
  int job = blockIdx.x;
  f32x4 acc[2][2] = {};
  if (job < GHT) {
    mfma_tile512<false>(bhS, blS, xh, xl, nullptr, DD, Wih, DD, job * 128, acc);
    store_tile512(acc, gi, G3, job * 128);
  } else {
    int g = job - GHT;
    mfma_tile512<false>(bhS, blS, hhi, hlo, nullptr, HH, Whh, HH, g * 128, acc);
    store_tile512(acc, gh, G3, g * 128);
  }
}

__global__ __launch_bounds__(512) void k_fuse(
    const float* __restrict__ gi, const float* __restrict__ gh,
    const float* __restrict__ bih, const float* __restrict__ bhh,
    float* __restrict__ h, ushort_t* __restrict__ hhi, ushort_t* __restrict__ hlo)
{
  int i = blockIdx.x * 512 + threadIdx.x;
  int b = i >> 10, j = i & 1023;
  fuse_elem(gi + (size_t)b * G3, gh + (size_t)b * G3, bih, bhh, h, hhi, hlo, b, j);
}

__global__ __launch_bounds__(512, 2) void k_logits(
    const ushort_t* __restrict__ hhi, const ushort_t* __restrict__ hlo,
    const float* __restrict__ fcw, const float* __restrict__ fcb,
    float* __restrict__ lg, u64* __restrict__ partial, int t)
{
  __shared__ ushort_t bhS[128][40];
  __shared__ ushort_t blS[128][40];
  __shared__ u64 scr[64][4];
  f32x4 acc[2][2] = {};
  mfma_tile512<false>(bhS, blS, hhi, hlo, nullptr, HH, fcw, HH, blockIdx.x * 128, acc);
  sample_epi512(acc, scr, fcb, lg, blockIdx.x * 128, partial, blockIdx.x, t);
}

__global__ __launch_bounds__(512) void k_finish(
    const u64* __restrict__ partial, const float* __restrict__ emb,
    float* __restrict__ idx_t, ushort_t* __restrict__ xh, ushort_t* __restrict__ xl)
{
  __shared__ u64 sred[512];
  const int b = blockIdx.x, tid = threadIdx.x;
  int idx = finish_reduce(partial, b, sred);
  if (tid == 0) idx_t[b] = (float)idx;
  float v = emb[(size_t)idx * DD + tid];
  uint32_t hb = f2bf(v);
  xh[(size_t)b * DD + tid] = (ushort_t)hb;
  xl[(size_t)b * DD + tid] = (ushort_t)f2bf(v - bf2f(hb));
}

extern "C" void kernel_launch(void* const* d_in, const int* in_sizes, int n_in,
                              void* d_out, int out_size, void* d_ws, size_t ws_size,
                              hipStream_t stream) {
  const float* seq = (const float*)d_in[0];
  const float* emb = (const float*)d_in[1];
  const float* Wih = (const float*)d_in[2];
  const float* Whh = (const float*)d_in[3];
  const float* bih = (const float*)d_in[4];
  const float* bhh = (const float*)d_in[5];
  const float* fcw = (const float*)d_in[6];
  const float* fcb = (const float*)d_in[7];
  const int*   eos = (const int*)d_in[8];

  float* out = (float*)d_out;
  float* idx_out = out;                              // [50][64] as float
  float* log_out = out + (size_t)T_STEPS * BB;       // [50][64][32000]

  uint8_t* wsp = (uint8_t*)d_ws;
  auto alloc = [&](size_t bytes) {
    uint8_t* p = wsp;
    wsp += (bytes + 255) & ~(size_t)255;
    return p;
  };
  float*    h    = (float*)alloc((size_t)BB * HH * 4);
  ushort_t* hhi  = (ushort_t*)alloc((size_t)BB * HH * 2);
  ushort_t* hlo  = (ushort_t*)alloc((size_t)BB * HH * 2);
  float*    gh   = (float*)alloc((size_t)BB * G3 * 4);
  float*    gi   = (float*)alloc((size_t)BB * G3 * 4);
  ushort_t* xh   = (ushort_t*)alloc((size_t)BB * DD * 2);
  ushort_t* xl   = (ushort_t*)alloc((size_t)BB * DD * 2);
  u64*      part = (u64*)alloc((size_t)BB * NT * 8);
  float*    U    = (float*)alloc((size_t)VV * G3 * 4);   // 393 MB, last

  size_t need_u = (size_t)((uint8_t*)wsp - (uint8_t*)d_ws);
  bool useU = need_u <= ws_size;

  const void* kfn = useU ? reinterpret_cast<const void*>(&decoder_all<true>)
                         : reinterpret_cast<const void*>(&decoder_all<false>);

  // capture-safe device/occupancy queries -> legal cooperative grid
  int dev = 0;
  (void)hipGetDevice(&dev);
  int numCU = 0;
  (void)hipDeviceGetAttribute(&numCU, hipDeviceAttributeMultiprocessorCount, dev);
  int occ = 0;
  hipError_t qe = hipOccupancyMaxActiveBlocksPerMultiprocessor(&occ, kfn, 512, 0);
  long grid = (qe == hipSuccess && numCU > 0) ? (long)occ * (long)numCU : 0;
  if (grid > 512) grid = 512;

  hipError_t err = hipErrorUnknown;
  if (grid >= 64) {
    void* args[] = {&seq, &emb, &Wih, &Whh, &bih, &bhh, &fcw, &fcb, &eos,
                    &idx_out, &log_out, &U, &h, &hhi, &hlo, &gh, &gi,
                    &xh, &xl, &part};
    err = hipLaunchCooperativeKernel(kfn, dim3((uint32_t)grid), dim3(512),
                                     args, 0, stream);
  }
  if (err != hipSuccess) {
    // proven multi-launch fallback (same device helpers)
    k_init<<<128, 512, 0, stream>>>(seq, emb, eos, h, hhi, hlo, xh, xl);
    for (int t = 0; t < T_STEPS; ++t) {
      float* lg = log_out + (size_t)t * BB * VV;
      k_gates<<<2 * GHT, 512, 0, stream>>>(xh, xl, hhi, hlo, Wih, Whh, gi, gh);
      k_fuse<<<128, 512, 0, stream>>>(gi, gh, bih, bhh, h, hhi, hlo);
      k_logits<<<NT, 512, 0, stream>>>(hhi, hlo, fcw, fcb, lg, part, t);
      k_finish<<<BB, 512, 0, stream>>>(part, emb, idx_out + (size_t)t * BB, xh, xl);
    }
  }
}